// Round 3
// baseline (355.487 us; speedup 1.0000x reference)
//
#include <hip/hip_runtime.h>

// LSTMP via MFMA, fp32 I/O, f16 compute, fp32 accumulate.
// B=4096, T=512, IN=4, HID=64, PROJ=52.
// Grid 512 x 256thr (4 waves), 8 batch/block -> TWO INDEPENDENT BLOCKS PER CU.
//
// Round-15: DECORRELATION. R13 proved stalls are barrier-correlated: 2
// waves/SIMD in ONE block gave +0% (stalls coincide between the shared
// barriers). Fix: two independent blocks per CU (separate barrier domains);
// their phases self-stagger via shared-pipe contention, so each block's
// ds-latency / MFMA-latency / trans-chain stalls are filled by the other
// block's issue.
//
// 8-batch blocks would waste half the lanes; instead each wave computes
// 16 hid as TWO gate-packed tile-pairs (4 tiles, 12 MFMA/step, cols 8-15
// dead) and a ds_swizzle(xor 8) REPACK pulls tile-pair s1's valid cols 0-7
// into lanes col>=8 -> all 64 lanes hold valid cells, 2 cells/lane,
// trans issue per SIMD conserved (40/step). Repack is a bit-exact f32 move;
// per-gate accumulate order (xb seed, M0, M1), scales and f16 RTNE identical
// to R12/R13 -> absmax exactly 9.765625e-4.
//   gates = (Whh@Whr)@d + [Wih|b]@[x;1]   (M precomputed per block, fp32)
// xb-MFMA now sits in the post-barrier ds_read shadow (same dataflow order).
// x staged to LDS as f16 once; d double-buffered (136B rows, rows 8-15 stay
// zero); ONE lgkm-only barrier/step; h only in epilogue (Whr@d_T).
// log2e folded (i,f,o rows xL; g rows x2L; c' = 2L*c).

#define T_STEPS 512
#define HID 64
#define NPROJ 52
#define NBATCH 8
#define ROWB 136
#define DROWS 16                   // b-frag reads rows 0..15; rows 8..15 stay zero
#define DBYTES (DROWS * ROWB)      // 2176 B per d buffer
#define XROWB 64                   // 8 batches x 8B per t
#define XBYTES (T_STEPS * XROWB)   // 32768 B
#define LOG2E 1.44269504088896340736f

typedef _Float16 half8 __attribute__((ext_vector_type(8)));
typedef float f32x4 __attribute__((ext_vector_type(4)));

__device__ __forceinline__ float exp2_f(float x) {
#if __has_builtin(__builtin_amdgcn_exp2f)
    return __builtin_amdgcn_exp2f(x);
#else
    return exp2f(x);
#endif
}
__device__ __forceinline__ float rcp_f(float x) {
    return __builtin_amdgcn_rcpf(x);
}

__global__ __launch_bounds__(256, 2)
void lstmp_kernel(const float* __restrict__ x,      // [4096][512][4]
                  const float* __restrict__ Wih,    // [256][4]
                  const float* __restrict__ Whh,    // [256][52]
                  const float* __restrict__ bih,    // [256]
                  const float* __restrict__ bhh,    // [256]
                  const float* __restrict__ Whr,    // [52][64]
                  float* __restrict__ out)          // [4096][52]
{
    __shared__ char lds[XBYTES + 2 * DBYTES];
    char* xl = lds;                 // x_lds: [t][b] 8B cells, 8 batches
    char* dl = lds + XBYTES;        // double-buffered d, [16 rows][136B]

    const int tid  = threadIdx.x;
    const int lane = tid & 63;
    const int wave = tid >> 6;           // 0..3, owns hid block [16w, 16w+16)
    const int quad = lane >> 4;
    const int col  = lane & 15;          // B/C col; cols 8-15 dead pre-repack

    // ---- zero d buffers (t=0 reads buffer 0 as d(-1)=0; rows 8-15 stay 0) --
    {
        unsigned* p = (unsigned*)dl;
        for (int i = tid; i < (int)(2 * DBYTES / 4); i += 256) p[i] = 0u;
    }

    // ---- stage x -> LDS as f16 (one-time; coalesced global reads) ----
    {
        const float4* xg = (const float4*)x + (size_t)blockIdx.x * NBATCH * T_STEPS;
        for (int i = tid; i < NBATCH * T_STEPS; i += 256) {
            const int b = i >> 9;          // global layout is b-major
            const int t = i & (T_STEPS - 1);
            const float4 v = xg[i];
            union { _Float16 h[4]; unsigned long long q; } u;
            u.h[0] = (_Float16)v.x; u.h[1] = (_Float16)v.y;
            u.h[2] = (_Float16)v.z; u.h[3] = (_Float16)v.w;
            *(unsigned long long*)(xl + t * XROWB + b * 8) = u.q;
        }
    }

    // ---- A-frag rows for the 4 tiles ----
    // tile T: {0:(s0,if), 1:(s0,go), 2:(s1,if), 3:(s1,go)}, sub-block s: hid
    // base 16w+8s. tile row tr -> gate (tr&1), hid = base + (tr>>1).
    const int hwb  = wave * 16 + (col >> 1);
    const int gsel = col & 1;
    int rowT[4];
    rowT[0] = gsel * HID + hwb;            // i/f, s0
    rowT[1] = (2 + gsel) * HID + hwb;      // g/o, s0
    rowT[2] = gsel * HID + hwb + 8;        // i/f, s1
    rowT[3] = (2 + gsel) * HID + hwb + 8;  // g/o, s1

    // ---- one-time: M = Whh @ Whr for the 4 packed rows (fp32) ----
    float macc[4][16];
#pragma unroll
    for (int g = 0; g < 4; ++g)
#pragma unroll
        for (int kk = 0; kk < 16; ++kk) macc[g][kk] = 0.0f;

    for (int p = 0; p < NPROJ; ++p) {
        float wv[4];
#pragma unroll
        for (int g = 0; g < 4; ++g) wv[g] = Whh[rowT[g] * NPROJ + p];
        const float* wr = Whr + p * HID + quad * 8;
        const float4 r0 = *(const float4*)(wr);
        const float4 r1 = *(const float4*)(wr + 4);
        const float4 r2 = *(const float4*)(wr + 32);
        const float4 r3 = *(const float4*)(wr + 36);
        const float rk[16] = {r0.x, r0.y, r0.z, r0.w, r1.x, r1.y, r1.z, r1.w,
                              r2.x, r2.y, r2.z, r2.w, r3.x, r3.y, r3.z, r3.w};
#pragma unroll
        for (int g = 0; g < 4; ++g)
#pragma unroll
            for (int kk = 0; kk < 16; ++kk) macc[g][kk] = fmaf(wv[g], rk[kk], macc[g][kk]);
    }

    // ---- fold log2e, convert to f16 A-frags ----
    // i,f,o rows scale L; g rows scale 2L (tiles 1,3 with gsel==0).
    float sT[4];
    sT[0] = LOG2E; sT[2] = LOG2E;
    sT[1] = (gsel == 0) ? (2.0f * LOG2E) : LOG2E;
    sT[3] = sT[1];
    half8 aM[4][2];   // M-part, K=64 (2 chunks)
    half8 aXB[4];     // [Wih | bias] part, K=32 (quad0: k<4 = x, k==4 = 1-col)
#pragma unroll
    for (int g = 0; g < 4; ++g) {
#pragma unroll
        for (int ch = 0; ch < 2; ++ch)
#pragma unroll
            for (int j = 0; j < 8; ++j)
                aM[g][ch][j] = (_Float16)(macc[g][ch * 8 + j] * sT[g]);
#pragma unroll
        for (int j = 0; j < 8; ++j) {
            const int k = quad * 8 + j;
            float v = 0.0f;
            if (k < 4)       v = Wih[rowT[g] * 4 + k];
            else if (k == 4) v = bih[rowT[g]] + bhh[rowT[g]];
            aXB[g][j] = (_Float16)(v * sT[g]);
        }
    }

    float cacc[2] = {0.0f, 0.0f};   // c' = 2L*c; cells hid = 16w+8*(col>>3)+2q+{0,1}

    // d write: batch = col&7, hid = 16w + 8*(col>>3) + 2q (+u), 2 f16 = b32
    const int dwoff  = (col & 7) * ROWB + wave * 32 + (col >> 3) * 16 + quad * 4;
    const int drbase = col * ROWB + quad * 16;             // d read base (+64 for ch1)
    const char* xrd  = xl + col * 8;                       // valid col<8 only
    const bool hi    = (col & 8) != 0;

    __syncthreads();   // staging + zeros visible

#pragma unroll 1
    for (int t = 0; t < T_STEPS; ++t) {
        const char* rbuf = dl + (t & 1) * DBYTES;
        char* wbuf = dl + ((t + 1) & 1) * DBYTES;

        // ---- post-barrier: issue d(t-1) reads; xb work fills their shadow --
        half8 bd0, bd1;
        {
            const char* p0 = rbuf + drbase;
            union { unsigned long long q[2]; half8 h; } u0, u1;
            u0.q[0] = *(const unsigned long long*)(p0);
            u0.q[1] = *(const unsigned long long*)(p0 + 8);
            u1.q[0] = *(const unsigned long long*)(p0 + 64);
            u1.q[1] = *(const unsigned long long*)(p0 + 72);
            bd0 = u0.h; bd1 = u1.h;
        }

        // xb-MFMA seeds gates(t) (accumulate order: xb, M0, M1 — as R12/R13)
        half8 bx;
#pragma unroll
        for (int j = 0; j < 8; ++j) bx[j] = (_Float16)0.0f;
        if (quad == 0 && col < NBATCH) {
            union { unsigned long long q; _Float16 h[4]; } u;
            u.q = *(const unsigned long long*)(xrd + t * XROWB);
            bx[0] = u.h[0]; bx[1] = u.h[1]; bx[2] = u.h[2]; bx[3] = u.h[3];
            bx[4] = (_Float16)1.0f;
        }
        const f32x4 z = {0.f, 0.f, 0.f, 0.f};
        f32x4 aT0 = __builtin_amdgcn_mfma_f32_16x16x32_f16(aXB[0], bx, z, 0, 0, 0);
        f32x4 aT1 = __builtin_amdgcn_mfma_f32_16x16x32_f16(aXB[1], bx, z, 0, 0, 0);
        f32x4 aT2 = __builtin_amdgcn_mfma_f32_16x16x32_f16(aXB[2], bx, z, 0, 0, 0);
        f32x4 aT3 = __builtin_amdgcn_mfma_f32_16x16x32_f16(aXB[3], bx, z, 0, 0, 0);

        aT0 = __builtin_amdgcn_mfma_f32_16x16x32_f16(aM[0][0], bd0, aT0, 0, 0, 0);
        aT1 = __builtin_amdgcn_mfma_f32_16x16x32_f16(aM[1][0], bd0, aT1, 0, 0, 0);
        aT2 = __builtin_amdgcn_mfma_f32_16x16x32_f16(aM[2][0], bd0, aT2, 0, 0, 0);
        aT3 = __builtin_amdgcn_mfma_f32_16x16x32_f16(aM[3][0], bd0, aT3, 0, 0, 0);
        aT0 = __builtin_amdgcn_mfma_f32_16x16x32_f16(aM[0][1], bd1, aT0, 0, 0, 0);
        aT1 = __builtin_amdgcn_mfma_f32_16x16x32_f16(aM[1][1], bd1, aT1, 0, 0, 0);
        aT2 = __builtin_amdgcn_mfma_f32_16x16x32_f16(aM[2][1], bd1, aT2, 0, 0, 0);
        aT3 = __builtin_amdgcn_mfma_f32_16x16x32_f16(aM[3][1], bd1, aT3, 0, 0, 0);

        // ---- repack: lanes col>=8 take tile-pair s1's cols 0-7 (xor-8) ----
        // Bit-exact f32 move; every lane then holds 2 valid cells.
        float p0v[4], p1v[4];
#pragma unroll
        for (int r = 0; r < 4; ++r) {
            const int s2 = __builtin_amdgcn_ds_swizzle(__float_as_int(aT2[r]), 0x201F);
            const int s3 = __builtin_amdgcn_ds_swizzle(__float_as_int(aT3[r]), 0x201F);
            p0v[r] = hi ? __int_as_float(s2) : aT0[r];
            p1v[r] = hi ? __int_as_float(s3) : aT1[r];
        }

        // ---- activations + cell update: 2 cells/lane, no garbage lanes ----
        // p0v = [i(c0), f(c0), i(c1), f(c1)], p1v = [g(c0), o(c0), g(c1), o(c1)]
        union { _Float16 h[2]; unsigned w; } du;
#pragma unroll
        for (int u = 0; u < 2; ++u) {
            const float iv = rcp_f(1.0f + exp2_f(-p0v[2 * u]));                   // sigmoid
            const float fv = rcp_f(1.0f + exp2_f(-p0v[2 * u + 1]));
            const float ov = rcp_f(1.0f + exp2_f(-p1v[2 * u + 1]));
            const float gs = fmaf(-4.0f * LOG2E, rcp_f(1.0f + exp2_f(p1v[2 * u])),
                                  2.0f * LOG2E);                                  // 2L*tanh(g)
            const float cn = fmaf(fv, cacc[u], iv * gs);                          // c' = 2L*c
            cacc[u] = cn;
            const float th = fmaf(-2.0f, rcp_f(1.0f + exp2_f(cn)), 1.0f);         // tanh(c)
            du.h[u] = (_Float16)(ov * th);                                        // RTNE
        }
        *(unsigned*)(wbuf + dwoff) = du.w;

        __syncthreads();   // the ONLY barrier per step (lgkm-only drain)
    }

    // ---- epilogue: h_T = Whr @ d(511); d(511) is in buffer 0 ----
    {
        half8 aP[2];
        const int prow = wave * 16 + col;
#pragma unroll
        for (int ch = 0; ch < 2; ++ch)
#pragma unroll
            for (int j = 0; j < 8; ++j) {
                const int k = ch * 32 + quad * 8 + j;
                aP[ch][j] = (_Float16)((prow < NPROJ) ? Whr[prow * HID + k] : 0.0f);
            }

        half8 bd0, bd1;
        {
            const char* p0 = dl + 0 * DBYTES + drbase;
            union { unsigned long long q[2]; half8 h; } u0, u1;
            u0.q[0] = *(const unsigned long long*)(p0);
            u0.q[1] = *(const unsigned long long*)(p0 + 8);
            u1.q[0] = *(const unsigned long long*)(p0 + 64);
            u1.q[1] = *(const unsigned long long*)(p0 + 72);
            bd0 = u0.h; bd1 = u1.h;
        }
        f32x4 hf = {0.f, 0.f, 0.f, 0.f};
        hf = __builtin_amdgcn_mfma_f32_16x16x32_f16(aP[0], bd0, hf, 0, 0, 0);
        hf = __builtin_amdgcn_mfma_f32_16x16x32_f16(aP[1], bd1, hf, 0, 0, 0);

        // store: p = wave*16 + quad*4 + r, batch = col (cols 0-7 valid)
        if (col < NBATCH) {
            const size_t bg = (size_t)blockIdx.x * NBATCH + col;
            float* o = out + bg * NPROJ;
            const int pb = wave * 16 + quad * 4;
#pragma unroll
            for (int r = 0; r < 4; ++r) {
                const int p = pb + r;
                if (p < NPROJ) o[p] = hf[r];
            }
        }
    }
}

extern "C" void kernel_launch(void* const* d_in, const int* in_sizes, int n_in,
                              void* d_out, int out_size, void* d_ws, size_t ws_size,
                              hipStream_t stream) {
    const float* x   = (const float*)d_in[0];
    const float* Wih = (const float*)d_in[1];
    const float* Whh = (const float*)d_in[2];
    const float* bih = (const float*)d_in[3];
    const float* bhh = (const float*)d_in[4];
    const float* Whr = (const float*)d_in[5];
    float* out = (float*)d_out;

    dim3 grid(4096 / NBATCH);   // 512 blocks -> 2 independent blocks per CU
    dim3 block(256);            // 4 waves
    lstmp_kernel<<<grid, block, 0, stream>>>(x, Wih, Whh, bih, bhh, Whr, out);
}

// Round 5
// 310.587 us; speedup vs baseline: 1.1446x; 1.1446x over previous
//
#include <hip/hip_runtime.h>

// LSTMP via MFMA, fp32 I/O, f16 compute, fp32 accumulate.
// B=4096, T=512, IN=4, HID=64, PROJ=52. Grid 256 x 512thr (8 waves, 2/SIMD),
// 16 batch/block.
//
// Round-16: PER-CELL GATE PACKING for deterministic MFMA||VALU overlap.
// R13/R15 post-mortem: step time is a SERIALIZED sum (read ~120 + MFMA
// window ~390 + VALU window ~550 + barrier ~80 ~= 1120 cyc) because waves
// are barrier-lockstepped: all read together, all MFMA together (VALU
// idle), all trans together (matrix idle). Fix the overlap INTRA-wave by
// dataflow: tile rows = [i,f,g,o] interleaved per hid (row = 4*hloc+gate),
// so a lane's f32x4 acc = all 4 gates of ONE cell. Tile0 completing
// enables trans(cell0) while tile1's MFMAs still occupy the matrix pipe;
// bx assembly + xb-MFMAs fill the post-barrier ds_read window.
//   wave owns hid [8w,8w+8): tile0 = hid 8w..8w+3, tile1 = 8w+4..8w+7.
//   lane(quad,col): cell0 = (hid 8w+quad, batch col), cell1 = (+4).
// Packing is a pure row permutation; per-gate accumulate order (xb seed,
// M0, M1), scales and f16 RTNE identical to R12/R13 -> absmax exactly
// 9.765625e-4.
//   gates = (Whh@Whr)@d + [Wih|b]@[x;1]   (M precomputed per block, fp32)
// x staged to LDS as f16 once; d double-buffered (136B rows, 0-conflict
// reads); ONE lgkm-only barrier/step; h only in epilogue (Whr@d_T).
// log2e folded (i,f,o rows xL; g rows x2L; c' = 2L*c).
//
// (Round-17 resubmit: R16 bench was an infra failure — container
// acquisition failed twice, no kernel signal. Source identical to R16.)

#define T_STEPS 512
#define HID 64
#define NPROJ 52
#define NBATCH 16
#define ROWB 136
#define DBYTES (NBATCH * ROWB)     // 2176 B per d buffer
#define XBYTES (T_STEPS * 128)     // 65536 B: x_lds[t][b] 8B cells (4 x f16)
#define LOG2E 1.44269504088896340736f

typedef _Float16 half8 __attribute__((ext_vector_type(8)));
typedef float f32x4 __attribute__((ext_vector_type(4)));

__device__ __forceinline__ float exp2_f(float x) {
#if __has_builtin(__builtin_amdgcn_exp2f)
    return __builtin_amdgcn_exp2f(x);
#else
    return exp2f(x);
#endif
}
__device__ __forceinline__ float rcp_f(float x) {
    return __builtin_amdgcn_rcpf(x);
}

__global__ __launch_bounds__(512, 2)
void lstmp_kernel(const float* __restrict__ x,      // [4096][512][4]
                  const float* __restrict__ Wih,    // [256][4]
                  const float* __restrict__ Whh,    // [256][52]
                  const float* __restrict__ bih,    // [256]
                  const float* __restrict__ bhh,    // [256]
                  const float* __restrict__ Whr,    // [52][64]
                  float* __restrict__ out)          // [4096][52]
{
    __shared__ char lds[XBYTES + 2 * DBYTES];
    char* xl = lds;                 // x_lds: [t][b] 8B cells
    char* dl = lds + XBYTES;        // double-buffered d, [16 batch][136B]

    const int tid  = threadIdx.x;
    const int lane = tid & 63;
    const int wave = tid >> 6;           // 0..7, owns hid block [8w, 8w+8)
    const int quad = lane >> 4;
    const int col  = lane & 15;          // batch (B/C col), A-frag row

    // ---- zero d buffers (t=0 reads buffer 0 as d(-1)=0) ----
    {
        unsigned* p = (unsigned*)dl;
        for (int i = tid; i < (int)(2 * DBYTES / 4); i += 512) p[i] = 0u;
    }

    // ---- stage x -> LDS as f16 (one-time; coalesced global reads) ----
    {
        const float4* xg = (const float4*)x + (size_t)blockIdx.x * NBATCH * T_STEPS;
        for (int i = tid; i < NBATCH * T_STEPS; i += 512) {
            const int b = i >> 9;          // global layout is b-major
            const int t = i & (T_STEPS - 1);
            const float4 v = xg[i];
            union { _Float16 h[4]; unsigned long long q; } u;
            u.h[0] = (_Float16)v.x; u.h[1] = (_Float16)v.y;
            u.h[2] = (_Float16)v.z; u.h[3] = (_Float16)v.w;
            *(unsigned long long*)(xl + t * 128 + b * 8) = u.q;
        }
    }

    // ---- A-frag rows: tile row r = 4*hloc + gate (per-cell interleave) ----
    // A-frag row for this lane = col -> hloc = col>>2, gate = col&3.
    // tile0: hid = 8w + hloc; tile1: hid = 8w + 4 + hloc.
    const int gate = col & 3;
    const int hl   = col >> 2;
    int rowT[2];
    rowT[0] = gate * HID + wave * 8 + hl;
    rowT[1] = rowT[0] + 4;

    // ---- one-time: M = Whh @ Whr for the 2 packed rows (fp32) ----
    float macc[2][16];
#pragma unroll
    for (int g = 0; g < 2; ++g)
#pragma unroll
        for (int kk = 0; kk < 16; ++kk) macc[g][kk] = 0.0f;

    for (int p = 0; p < NPROJ; ++p) {
        const float w0 = Whh[rowT[0] * NPROJ + p];
        const float w1 = Whh[rowT[1] * NPROJ + p];
        const float* wr = Whr + p * HID + quad * 8;
        const float4 r0 = *(const float4*)(wr);
        const float4 r1 = *(const float4*)(wr + 4);
        const float4 r2 = *(const float4*)(wr + 32);
        const float4 r3 = *(const float4*)(wr + 36);
        const float rk[16] = {r0.x, r0.y, r0.z, r0.w, r1.x, r1.y, r1.z, r1.w,
                              r2.x, r2.y, r2.z, r2.w, r3.x, r3.y, r3.z, r3.w};
#pragma unroll
        for (int kk = 0; kk < 16; ++kk) {
            macc[0][kk] = fmaf(w0, rk[kk], macc[0][kk]);
            macc[1][kk] = fmaf(w1, rk[kk], macc[1][kk]);
        }
    }

    // ---- fold log2e, convert to f16 A-frags ----
    const float sc = (gate == 2) ? (2.0f * LOG2E) : LOG2E;   // g rows x2L
    half8 aM[2][2];   // [tile][K-chunk]
    half8 aXB[2];     // [Wih | bias] part, K=32 (quad0: k<4 = x, k==4 = 1-col)
#pragma unroll
    for (int g = 0; g < 2; ++g) {
#pragma unroll
        for (int ch = 0; ch < 2; ++ch)
#pragma unroll
            for (int j = 0; j < 8; ++j)
                aM[g][ch][j] = (_Float16)(macc[g][ch * 8 + j] * sc);
#pragma unroll
        for (int j = 0; j < 8; ++j) {
            const int k = quad * 8 + j;
            float v = 0.0f;
            if (k < 4)       v = Wih[rowT[g] * 4 + k];
            else if (k == 4) v = bih[rowT[g]] + bhh[rowT[g]];
            aXB[g][j] = (_Float16)(v * sc);
        }
    }

    float cacc[2] = {0.0f, 0.0f};   // c' = 2L*c; cell0 hid 8w+quad, cell1 +4

    const int dwoff  = col * ROWB + wave * 16 + quad * 2;  // cell0 d (b16); cell1 +8
    const int drbase = col * ROWB + quad * 16;             // d read base (+64 ch1)
    const char* xrd  = xl + col * 8;                       // + t*128 per step

    __syncthreads();   // staging + zeros visible

#pragma unroll 1
    for (int t = 0; t < T_STEPS; ++t) {
        const char* rbuf = dl + (t & 1) * DBYTES;
        char* wbuf = dl + ((t + 1) & 1) * DBYTES;

        // ---- post-barrier: issue x + d reads; bx assembly fills latency ----
        union { unsigned long long q; _Float16 h[4]; } xu;
        xu.q = (quad == 0) ? *(const unsigned long long*)(xrd + t * 128) : 0ull;

        half8 bd0, bd1;
        {
            const char* p0 = rbuf + drbase;
            union { unsigned long long q[2]; half8 h; } u0, u1;
            u0.q[0] = *(const unsigned long long*)(p0);
            u0.q[1] = *(const unsigned long long*)(p0 + 8);
            u1.q[0] = *(const unsigned long long*)(p0 + 64);
            u1.q[1] = *(const unsigned long long*)(p0 + 72);
            bd0 = u0.h; bd1 = u1.h;
        }

        half8 bx;
#pragma unroll
        for (int j = 0; j < 8; ++j) bx[j] = (_Float16)0.0f;
        if (quad == 0) {
            bx[0] = xu.h[0]; bx[1] = xu.h[1]; bx[2] = xu.h[2]; bx[3] = xu.h[3];
            bx[4] = (_Float16)1.0f;
        }

        // ---- xb seeds (matrix pipe fills read window), then M-MFMA ----
        // accumulate order per output: xb, M0(bd0), M1(bd1) — as R12/R13.
        const f32x4 z = {0.f, 0.f, 0.f, 0.f};
        f32x4 a0 = __builtin_amdgcn_mfma_f32_16x16x32_f16(aXB[0], bx, z, 0, 0, 0);
        f32x4 a1 = __builtin_amdgcn_mfma_f32_16x16x32_f16(aXB[1], bx, z, 0, 0, 0);

        a0 = __builtin_amdgcn_mfma_f32_16x16x32_f16(aM[0][0], bd0, a0, 0, 0, 0);
        a1 = __builtin_amdgcn_mfma_f32_16x16x32_f16(aM[1][0], bd0, a1, 0, 0, 0);
        a0 = __builtin_amdgcn_mfma_f32_16x16x32_f16(aM[0][1], bd1, a0, 0, 0, 0);
        a1 = __builtin_amdgcn_mfma_f32_16x16x32_f16(aM[1][1], bd1, a1, 0, 0, 0);

        // ---- trans(cell0) overlaps tile1's in-flight MFMAs ----
        // a = [i, f, g, o] of one cell; no cross-lane, no repack.
        {
            const float iv = rcp_f(1.0f + exp2_f(-a0[0]));
            const float fv = rcp_f(1.0f + exp2_f(-a0[1]));
            const float gs = fmaf(-4.0f * LOG2E, rcp_f(1.0f + exp2_f(a0[2])),
                                  2.0f * LOG2E);
            const float ov = rcp_f(1.0f + exp2_f(-a0[3]));
            const float cn = fmaf(fv, cacc[0], iv * gs);
            cacc[0] = cn;
            const float th = fmaf(-2.0f, rcp_f(1.0f + exp2_f(cn)), 1.0f);
            *(_Float16*)(wbuf + dwoff) = (_Float16)(ov * th);     // RTNE
        }
        {
            const float iv = rcp_f(1.0f + exp2_f(-a1[0]));
            const float fv = rcp_f(1.0f + exp2_f(-a1[1]));
            const float gs = fmaf(-4.0f * LOG2E, rcp_f(1.0f + exp2_f(a1[2])),
                                  2.0f * LOG2E);
            const float ov = rcp_f(1.0f + exp2_f(-a1[3]));
            const float cn = fmaf(fv, cacc[1], iv * gs);
            cacc[1] = cn;
            const float th = fmaf(-2.0f, rcp_f(1.0f + exp2_f(cn)), 1.0f);
            *(_Float16*)(wbuf + dwoff + 8) = (_Float16)(ov * th); // RTNE
        }

        __syncthreads();   // the ONLY barrier per step (lgkm-only drain)
    }

    // ---- epilogue: h_T = Whr @ d(511); d(511) is in buffer 0; waves 0-3 ----
    if (wave < 4) {
        half8 aP[2];
        const int prow = wave * 16 + col;
#pragma unroll
        for (int ch = 0; ch < 2; ++ch)
#pragma unroll
            for (int j = 0; j < 8; ++j) {
                const int k = ch * 32 + quad * 8 + j;
                aP[ch][j] = (_Float16)((prow < NPROJ) ? Whr[prow * HID + k] : 0.0f);
            }

        half8 bd0, bd1;
        {
            const char* p0 = dl + 0 * DBYTES + drbase;
            union { unsigned long long q[2]; half8 h; } u0, u1;
            u0.q[0] = *(const unsigned long long*)(p0);
            u0.q[1] = *(const unsigned long long*)(p0 + 8);
            u1.q[0] = *(const unsigned long long*)(p0 + 64);
            u1.q[1] = *(const unsigned long long*)(p0 + 72);
            bd0 = u0.h; bd1 = u1.h;
        }
        f32x4 hf = {0.f, 0.f, 0.f, 0.f};
        hf = __builtin_amdgcn_mfma_f32_16x16x32_f16(aP[0], bd0, hf, 0, 0, 0);
        hf = __builtin_amdgcn_mfma_f32_16x16x32_f16(aP[1], bd1, hf, 0, 0, 0);

        // store: p = wave*16 + quad*4 + r, batch = col  (wave 3: only quad 0 valid)
        const size_t bg = (size_t)blockIdx.x * NBATCH + col;
        float* o = out + bg * NPROJ;
        const int p0 = wave * 16 + quad * 4;
#pragma unroll
        for (int r = 0; r < 4; ++r) {
            const int p = p0 + r;
            if (p < NPROJ) o[p] = hf[r];
        }
    }
}

extern "C" void kernel_launch(void* const* d_in, const int* in_sizes, int n_in,
                              void* d_out, int out_size, void* d_ws, size_t ws_size,
                              hipStream_t stream) {
    const float* x   = (const float*)d_in[0];
    const float* Wih = (const float*)d_in[1];
    const float* Whh = (const float*)d_in[2];
    const float* bih = (const float*)d_in[3];
    const float* bhh = (const float*)d_in[4];
    const float* Whr = (const float*)d_in[5];
    float* out = (float*)d_out;

    dim3 grid(4096 / NBATCH);   // 256 blocks, 1 per CU
    dim3 block(512);            // 8 waves, 2 waves/SIMD
    lstmp_kernel<<<grid, block, 0, stream>>>(x, Wih, Whh, bih, bhh, Whr, out);
}